// Round 3
// baseline (309.805 us; speedup 1.0000x reference)
//
#include <hip/hip_runtime.h>
#include <hip/hip_cooperative_groups.h>

namespace cg = cooperative_groups;
typedef unsigned long long ull;

constexpr int N   = 500;
constexpr int HW  = 60800;    // 200*304
constexpr int NW  = 950;      // HW/64 (exact)
constexpr int NC  = 80;       // num classes
constexpr int NB  = 256;      // blocks (1 per CU, cooperative-resident)
constexpr int NT  = 512;      // threads per block (8 waves)
constexpr int NTILES = N * NW / 4;    // 118,750 pack tiles (256 px each)
constexpr int NQ  = N * (HW / 4);     // 7,600,000 float4 output quads

__global__ void __launch_bounds__(NT, 1)
k_all(const float* __restrict__ mp, const int* __restrict__ labels,
      const float* __restrict__ scores,
      ull* __restrict__ packed, int* __restrict__ order_g,
      int* __restrict__ pairCount_g, int2* __restrict__ pairList,
      float* __restrict__ iou, int* __restrict__ keepOrig_g,
      float* __restrict__ outScores, float* __restrict__ outLabels,
      float4* __restrict__ outMasks, float* __restrict__ outKeep) {
    cg::grid_group grid = cg::this_grid();

    __shared__ float sS[N];        // raw scores (by original idx), then reused
    __shared__ float scoS[N];      // sorted scores
    __shared__ int   labS[N];      // sorted labels
    __shared__ int   orderS[N];    // sorted -> original
    __shared__ float compS[N];
    __shared__ float sdec[N];
    __shared__ int   cnt[NC];
    __shared__ int   offs[NC + 1];
    __shared__ int   members[N];   // per-class CSR of sorted indices
    __shared__ int   pcnt;

    const int t    = threadIdx.x;
    const int lane = t & 63;

    // ---- Phase 1: pack (blocks 1..NB-1)  ||  sort + CSR + pairs (block 0) ----
    if (blockIdx.x != 0) {
        int wid    = (blockIdx.x - 1) * (NT / 64) + (t >> 6);
        int nwaves = (NB - 1) * (NT / 64);
        for (int tile = wid; tile < NTILES; tile += nwaves) {
            size_t base = (size_t)tile * 256;
            float v0 = mp[base +   0 + lane];
            float v1 = mp[base +  64 + lane];
            float v2 = mp[base + 128 + lane];
            float v3 = mp[base + 192 + lane];
            ull b0 = __ballot(v0 > 0.5f);
            ull b1 = __ballot(v1 > 0.5f);
            ull b2 = __ballot(v2 > 0.5f);
            ull b3 = __ballot(v3 > 0.5f);
            if (lane == 0) {
                longlong4 w;
                w.x = (long long)b0; w.y = (long long)b1;
                w.z = (long long)b2; w.w = (long long)b3;
                *(longlong4*)(packed + tile * 4) = w;
            }
        }
    } else {
        // stable descending rank-sort by score
        if (t < N) sS[t] = scores[t];
        if (t < NC) cnt[t] = 0;
        if (t == 0) pcnt = 0;
        __syncthreads();
        if (t < N) {
            float si = sS[t];
            int rank = 0;
            for (int j = 0; j < N; ++j) {
                float sj = sS[j];
                if (sj > si || (sj == si && j < t)) rank++;
            }
            orderS[rank] = t;
        }
        __syncthreads();
        if (t < N) {
            int o = orderS[t];
            scoS[t]    = sS[o];
            labS[t]    = labels[o];
            order_g[t] = o;
        }
        __syncthreads();
        if (t < N) atomicAdd(&cnt[labS[t]], 1);
        __syncthreads();
        if (t == 0) {
            int s = 0;
            for (int c = 0; c < NC; ++c) { offs[c] = s; s += cnt[c]; }
            offs[NC] = s;
        }
        __syncthreads();
        if (t < NC) cnt[t] = offs[t];        // insertion cursors
        __syncthreads();
        if (t < N) { int p = atomicAdd(&cnt[labS[t]], 1); members[p] = t; }
        __syncthreads();
        if (t < NC) {                        // enumerate same-class pairs (i<j)
            int b = offs[t], e = offs[t + 1];
            for (int a = b; a < e; ++a)
                for (int c2 = a + 1; c2 < e; ++c2) {
                    int i = members[a], j = members[c2];
                    int lo = min(i, j), hi = max(i, j);
                    int p = atomicAdd(&pcnt, 1);
                    pairList[p] = make_int2(lo, hi);
                }
        }
        __syncthreads();
        if (t == 0) *pairCount_g = pcnt;
    }
    __threadfence();
    grid.sync();

    // ---- Phase 2: IoU per pair (wave per pair; popcount A, B, A&B together) ----
    {
        int gw     = blockIdx.x * (NT / 64) + (t >> 6);
        int nwaves = NB * (NT / 64);
        int np     = *pairCount_g;
        for (int p = gw; p < np; p += nwaves) {
            int2 pr = pairList[p];
            const ull* A = packed + (size_t)order_g[pr.x] * NW;
            const ull* B = packed + (size_t)order_g[pr.y] * NW;
            ull acc = 0;  // ci | ca<<21 | cb<<42  (each field < 2^17)
            for (int w = lane; w < NW; w += 64) {
                ull a = A[w], b = B[w];
                acc += (ull)__popcll(a & b)
                     + ((ull)__popcll(a) << 21)
                     + ((ull)__popcll(b) << 42);
            }
#pragma unroll
            for (int off = 32; off > 0; off >>= 1) acc += __shfl_down(acc, off, 64);
            if (lane == 0) {
                float inter = (float)(int)(acc & 0x1FFFFF);
                float areaA = (float)(int)((acc >> 21) & 0x1FFFFF);
                float areaB = (float)(int)((acc >> 42) & 0x1FFFFF);
                float uni   = areaA + areaB - inter;   // exact ints in float
                iou[pr.x * N + pr.y] = inter / uni;
            }
        }
    }
    __threadfence();
    grid.sync();

    // ---- Phase 3: comp / decay coefficient / re-sort (block 0; CSR in LDS) ----
    if (blockIdx.x == 0) {
        if (t < N) {                         // comp[j] = max_{i<j same class} iou
            int lj = labS[t];
            float m = 0.f;
            int b = offs[lj], e = offs[lj + 1];
            for (int q = b; q < e; ++q) {
                int i = members[q];
                if (i < t) m = fmaxf(m, iou[i * N + t]);
            }
            compS[t] = m;
        }
        __syncthreads();
        if (t < N) {                         // coefficient (1 bounds the min)
            int lj = labS[t];
            float c = 1.f;
            int b = offs[lj], e = offs[lj + 1];
            for (int q = b; q < e; ++q) {
                int i = members[q];
                if (i < t) {
                    float d  = iou[i * N + t];
                    float ci = compS[i];
                    c = fminf(c, expf(-2.f * d * d) / expf(-2.f * ci * ci));  // mirror np
                }
            }
            sdec[t] = scoS[t] * c;
        }
        __syncthreads();
        if (t < N) {                         // stable descending rank on decayed scores
            float sj = sdec[t];
            int rank = 0;
            for (int i = 0; i < N; ++i) {
                float si = sdec[i];
                if (si > sj || (si == sj && i < t)) rank++;
            }
            int o = orderS[t];
            outScores[rank]  = sj;
            outLabels[rank]  = (float)labS[t];
            outKeep[rank]    = (float)o;
            keepOrig_g[rank] = o;
        }
    }
    __threadfence();
    grid.sync();

    // ---- Phase 4: expand kept masks to float output (float4 stores) ----
    {
        int stride = NB * NT;
        for (int gid = blockIdx.x * NT + t; gid < NQ; gid += stride) {
            int k   = gid / (HW / 4);
            int q   = gid - k * (HW / 4);
            int pix = q * 4;
            int orig = keepOrig_g[k];
            ull w  = packed[(size_t)orig * NW + (pix >> 6)];
            int sh = pix & 63;
            float4 r;
            r.x = (float)((w >> (sh    )) & 1ULL);
            r.y = (float)((w >> (sh + 1)) & 1ULL);
            r.z = (float)((w >> (sh + 2)) & 1ULL);
            r.w = (float)((w >> (sh + 3)) & 1ULL);
            outMasks[gid] = r;
        }
    }
}

// ---------------------------------------------------------------------------
extern "C" void kernel_launch(void* const* d_in, const int* in_sizes, int n_in,
                              void* d_out, int out_size, void* d_ws, size_t ws_size,
                              hipStream_t stream) {
    const float* mask_preds = (const float*)d_in[0];
    const int*   labels     = (const int*)d_in[1];
    const float* scores     = (const float*)d_in[2];

    float*  o         = (float*)d_out;
    float*  outScores = o;
    float*  outLabels = o + N;
    float4* outMasks  = (float4*)(o + 2 * N);
    float*  outKeep   = o + 2 * N + (size_t)N * HW;

    // workspace carve-up (16B-aligned chunks; ~5.8 MB total)
    char* w = (char*)d_ws;
    ull*   packed     = (ull*)w;   w += (size_t)N * NW * 8;            // 3,800,000
    int*   order_g    = (int*)w;   w += N * 4;
    int*   keepOrig_g = (int*)w;   w += N * 4;
    int*   pairCount  = (int*)w;   w += 16;
    int2*  pairList   = (int2*)w;  w += (size_t)(N * (N - 1) / 2) * 8; // 998,000
    float* iou        = (float*)w; /* N*N*4 = 1,000,000 */

    void* args[] = {
        (void*)&mask_preds, (void*)&labels, (void*)&scores,
        (void*)&packed, (void*)&order_g, (void*)&pairCount, (void*)&pairList,
        (void*)&iou, (void*)&keepOrig_g,
        (void*)&outScores, (void*)&outLabels, (void*)&outMasks, (void*)&outKeep
    };
    hipLaunchCooperativeKernel((void*)k_all, dim3(NB), dim3(NT), args, 0, stream);
}

// Round 4
// 88.571 us; speedup vs baseline: 3.4978x; 3.4978x over previous
//
#include <hip/hip_runtime.h>

typedef unsigned long long ull;

constexpr int N   = 500;
constexpr int HW  = 60800;    // 200*304
constexpr int NW  = 950;      // HW/64 (exact)
constexpr int NC  = 80;       // num classes
constexpr int NTILES = N * NW / 4;   // 118,750 pack tiles (256 px each)
constexpr int PB  = 1024;     // pack blocks (block 0 does the sort instead)
constexpr int QPB = (HW / 4 + 255) / 256;   // 60 blocks of quads per instance

// ---------------------------------------------------------------------------
// 1) Block 0: stable score sort + per-class CSR + same-class pair list.
//    Blocks 1..PB: binarize + bit-pack mask_preds (grid-strided waves).
__global__ void __launch_bounds__(512)
k_packsort(const float* __restrict__ mp, const int* __restrict__ labels,
           const float* __restrict__ scores,
           ull* __restrict__ packed, int* __restrict__ order_g,
           float* __restrict__ scoresS_g, int* __restrict__ labelsS_g,
           int* __restrict__ offs_g, int* __restrict__ members_g,
           int2* __restrict__ pairList, int* __restrict__ pairCount_g) {
    const int t    = threadIdx.x;
    const int lane = t & 63;

    if (blockIdx.x != 0) {
        // ---- pack ----
        int wid    = (blockIdx.x - 1) * 8 + (t >> 6);
        int nwaves = PB * 8;
        for (int tile = wid; tile < NTILES; tile += nwaves) {
            size_t base = (size_t)tile * 256;
            float v0 = mp[base +   0 + lane];
            float v1 = mp[base +  64 + lane];
            float v2 = mp[base + 128 + lane];
            float v3 = mp[base + 192 + lane];
            ull b0 = __ballot(v0 > 0.5f);
            ull b1 = __ballot(v1 > 0.5f);
            ull b2 = __ballot(v2 > 0.5f);
            ull b3 = __ballot(v3 > 0.5f);
            if (lane == 0) {
                longlong4 w;
                w.x = (long long)b0; w.y = (long long)b1;
                w.z = (long long)b2; w.w = (long long)b3;
                *(longlong4*)(packed + tile * 4) = w;
            }
        }
        return;
    }

    // ---- block 0: sort + CSR + pairs ----
    __shared__ float sS[N];
    __shared__ int   orderS[N];
    __shared__ int   labS[N];
    __shared__ int   cnt[NC];
    __shared__ int   offs[NC + 1];
    __shared__ int   members[N];
    __shared__ int   pcnt;

    if (t < N) sS[t] = scores[t];
    if (t < NC) cnt[t] = 0;
    if (t == 0) pcnt = 0;
    __syncthreads();
    if (t < N) {                       // stable descending rank sort
        float si = sS[t];
        int rank = 0;
        for (int j = 0; j < N; ++j) {
            float sj = sS[j];
            if (sj > si || (sj == si && j < t)) rank++;
        }
        orderS[rank] = t;
    }
    __syncthreads();
    if (t < N) {
        int o = orderS[t];
        order_g[t]   = o;
        scoresS_g[t] = sS[o];
        int l = labels[o];
        labS[t] = l;
        labelsS_g[t] = l;
    }
    __syncthreads();
    if (t < N) atomicAdd(&cnt[labS[t]], 1);
    __syncthreads();
    if (t == 0) {
        int s = 0;
        for (int c = 0; c < NC; ++c) { offs[c] = s; s += cnt[c]; }
        offs[NC] = s;
    }
    __syncthreads();
    if (t < NC) cnt[t] = offs[t];      // insertion cursors
    __syncthreads();
    if (t < N) { int p = atomicAdd(&cnt[labS[t]], 1); members[p] = t; }
    __syncthreads();
    if (t < NC) {                      // enumerate same-class pairs (i<j)
        int b = offs[t], e = offs[t + 1];
        for (int a = b; a < e; ++a)
            for (int c2 = a + 1; c2 < e; ++c2) {
                int i = members[a], j = members[c2];
                int lo = min(i, j), hi = max(i, j);
                int p = atomicAdd(&pcnt, 1);
                pairList[p] = make_int2(lo, hi);
            }
    }
    __syncthreads();
    if (t <= NC) offs_g[t] = offs[t];
    if (t < N)   members_g[t] = members[t];
    if (t == 0)  *pairCount_g = pcnt;
}

// ---------------------------------------------------------------------------
// 2) IoU per pair (wave per pair): popcount A, B, A&B in one packed acc.
__global__ void k_iou(const ull* __restrict__ packed, const int* __restrict__ order,
                      const int* __restrict__ pairCount, const int2* __restrict__ pairList,
                      float* __restrict__ iou) {
    int gw     = (blockIdx.x * blockDim.x + threadIdx.x) >> 6;
    int lane   = threadIdx.x & 63;
    int nwaves = (gridDim.x * blockDim.x) >> 6;
    int np     = *pairCount;
    for (int p = gw; p < np; p += nwaves) {
        int2 pr = pairList[p];
        const ull* A = packed + (size_t)order[pr.x] * NW;
        const ull* B = packed + (size_t)order[pr.y] * NW;
        ull acc = 0;  // inter | areaA<<21 | areaB<<42  (fields < 2^17)
        for (int w = lane; w < NW; w += 64) {
            ull a = A[w], b = B[w];
            acc += (ull)__popcll(a & b)
                 + ((ull)__popcll(a) << 21)
                 + ((ull)__popcll(b) << 42);
        }
#pragma unroll
        for (int off = 32; off > 0; off >>= 1) acc += __shfl_down(acc, off, 64);
        if (lane == 0) {
            float inter = (float)(int)(acc & 0x1FFFFF);
            float areaA = (float)(int)((acc >> 21) & 0x1FFFFF);
            float areaB = (float)(int)((acc >> 42) & 0x1FFFFF);
            float uni   = areaA + areaB - inter;     // exact small ints in float
            iou[pr.x * N + pr.y] = inter / uni;
        }
    }
}

// ---------------------------------------------------------------------------
// 3) comp / decay coefficient / stable re-sort (single block, CSR from global).
__global__ void __launch_bounds__(512)
k_decay(const int* __restrict__ labelsS_g, const float* __restrict__ scoresS_g,
        const int* __restrict__ offs_g, const int* __restrict__ members_g,
        const int* __restrict__ order_g, const float* __restrict__ iou,
        float* __restrict__ outScores, float* __restrict__ outLabels,
        float* __restrict__ outKeep, int* __restrict__ keepOrig_g) {
    __shared__ int   labS[N];
    __shared__ float compS[N];
    __shared__ float sdec[N];
    __shared__ int   offs[NC + 1];
    __shared__ int   members[N];
    int t = threadIdx.x;
    if (t < N)  { labS[t] = labelsS_g[t]; members[t] = members_g[t]; }
    if (t <= NC) offs[t] = offs_g[t];
    __syncthreads();
    if (t < N) {                        // comp[j] = max_{i<j same class} iou[i,j]
        int lj = labS[t];
        float m = 0.f;
        int b = offs[lj], e = offs[lj + 1];
        for (int q = b; q < e; ++q) {
            int i = members[q];
            if (i < t) m = fmaxf(m, iou[i * N + t]);
        }
        compS[t] = m;
    }
    __syncthreads();
    if (t < N) {                        // coefficient (1 bounds the min)
        int lj = labS[t];
        float c = 1.f;
        int b = offs[lj], e = offs[lj + 1];
        for (int q = b; q < e; ++q) {
            int i = members[q];
            if (i < t) {
                float d  = iou[i * N + t];
                float ci = compS[i];
                c = fminf(c, expf(-2.f * d * d) / expf(-2.f * ci * ci));  // mirror np
            }
        }
        sdec[t] = scoresS_g[t] * c;
    }
    __syncthreads();
    if (t < N) {                        // stable descending rank on decayed scores
        float sj = sdec[t];
        int rank = 0;
        for (int i = 0; i < N; ++i) {
            float si = sdec[i];
            if (si > sj || (si == sj && i < t)) rank++;
        }
        int o = order_g[t];
        outScores[rank]  = sj;
        outLabels[rank]  = (float)labS[t];
        outKeep[rank]    = (float)o;
        keepOrig_g[rank] = o;
    }
}

// ---------------------------------------------------------------------------
// 4) Expand kept masks to float output. 2D grid: y = output instance (no div).
__global__ void k_gather(const ull* __restrict__ packed, const int* __restrict__ keepOrig,
                         float4* __restrict__ outMasks) {
    int q = blockIdx.x * blockDim.x + threadIdx.x;   // quad within instance
    if (q >= HW / 4) return;
    int k    = blockIdx.y;
    int orig = keepOrig[k];                          // uniform -> scalar load
    int pix  = q * 4;
    ull w  = packed[(size_t)orig * NW + (pix >> 6)];
    int sh = pix & 63;
    float4 r;
    r.x = (float)((w >> (sh    )) & 1ULL);
    r.y = (float)((w >> (sh + 1)) & 1ULL);
    r.z = (float)((w >> (sh + 2)) & 1ULL);
    r.w = (float)((w >> (sh + 3)) & 1ULL);
    outMasks[(size_t)k * (HW / 4) + q] = r;
}

// ---------------------------------------------------------------------------
extern "C" void kernel_launch(void* const* d_in, const int* in_sizes, int n_in,
                              void* d_out, int out_size, void* d_ws, size_t ws_size,
                              hipStream_t stream) {
    const float* mask_preds = (const float*)d_in[0];
    const int*   labels     = (const int*)d_in[1];
    const float* scores     = (const float*)d_in[2];

    float*  o         = (float*)d_out;
    float*  outScores = o;
    float*  outLabels = o + N;
    float4* outMasks  = (float4*)(o + 2 * N);
    float*  outKeep   = o + 2 * N + (size_t)N * HW;

    // workspace carve-up (16B-aligned chunks; ~5.8 MB total)
    char* w = (char*)d_ws;
    ull*   packed     = (ull*)w;   w += (size_t)N * NW * 8;            // 3,800,000
    int*   order_g    = (int*)w;   w += N * 4;
    float* scoresS_g  = (float*)w; w += N * 4;
    int*   labelsS_g  = (int*)w;   w += N * 4;
    int*   offs_g     = (int*)w;   w += (NC + 4) * 4;
    int*   members_g  = (int*)w;   w += N * 4;
    int*   keepOrig_g = (int*)w;   w += N * 4;
    int*   pairCount  = (int*)w;   w += 16;
    int2*  pairList   = (int2*)w;  w += (size_t)(N * (N - 1) / 2) * 8; // 998,000
    float* iou        = (float*)w; /* N*N*4 = 1,000,000 */

    hipLaunchKernelGGL(k_packsort, dim3(PB + 1), dim3(512), 0, stream,
                       mask_preds, labels, scores, packed, order_g,
                       scoresS_g, labelsS_g, offs_g, members_g, pairList, pairCount);
    hipLaunchKernelGGL(k_iou, dim3(256), dim3(256), 0, stream,
                       packed, order_g, pairCount, pairList, iou);
    hipLaunchKernelGGL(k_decay, dim3(1), dim3(512), 0, stream,
                       labelsS_g, scoresS_g, offs_g, members_g, order_g, iou,
                       outScores, outLabels, outKeep, keepOrig_g);
    hipLaunchKernelGGL(k_gather, dim3(QPB, N), dim3(256), 0, stream,
                       packed, keepOrig_g, outMasks);
}